// Round 2
// baseline (249.814 us; speedup 1.0000x reference)
//
#include <hip/hip_runtime.h>

#define EPS 1e-5f
#define LOG2E 1.4426950408889634f

// One block per (B,C) channel: 512 blocks x 256 threads.
// Channel = 256x256 floats = 16384 float4. Thread t handles float4 indices
// f = 256*k + t, k=0..63. Column group pc=(t&63)>>4 is FIXED per thread;
// patch-row pr = k>>4. So phase-1 stats need only 16-lane butterflies.
__global__ __launch_bounds__(256) void k_fused(const float4* __restrict__ x4,
                                               const float* __restrict__ lw,
                                               float4* __restrict__ out4) {
    const int bc   = blockIdx.x;
    const int t    = threadIdx.x;
    const int wave = t >> 6;
    const int lane = t & 63;
    const int pc   = lane >> 4;          // patch-col group 0..3 (fixed per thread)
    const long base = (long)bc << 14;    // float4 offset of this channel

    __shared__ float2 red[4][16];        // [wave][pr*4+pc] partial sums
    __shared__ float2 psum[16];          // per-64x64-patch (sum, sumsq)
    __shared__ float2 coef[21];          // (A=-rstd*log2e, B=mu*rstd*log2e) x 21 slots

    // ---- Phase 1: stats ----
    float2 acc[4];
#pragma unroll
    for (int pr = 0; pr < 4; ++pr) {
        float s = 0.f, q = 0.f;
#pragma unroll
        for (int kk = 0; kk < 16; ++kk) {
            const float4 v = x4[base + (pr * 16 + kk) * 256 + t];
            s += v.x + v.y + v.z + v.w;
            q += v.x * v.x + v.y * v.y + v.z * v.z + v.w * v.w;
        }
        acc[pr] = make_float2(s, q);
    }
    // butterfly over the 16 lanes sharing this pc
#pragma unroll
    for (int off = 1; off < 16; off <<= 1) {
#pragma unroll
        for (int pr = 0; pr < 4; ++pr) {
            acc[pr].x += __shfl_xor(acc[pr].x, off, 64);
            acc[pr].y += __shfl_xor(acc[pr].y, off, 64);
        }
    }
    if ((lane & 15) == 0) {
#pragma unroll
        for (int pr = 0; pr < 4; ++pr) red[wave][pr * 4 + pc] = acc[pr];
    }
    __syncthreads();
    if (t < 16) {
        float2 s = red[0][t];
#pragma unroll
        for (int w = 1; w < 4; ++w) { s.x += red[w][t].x; s.y += red[w][t].y; }
        psum[t] = s;
    }
    __syncthreads();
    if (t < 21) {
        float sum, sq, n;
        if (t < 16) {                    // p=2: one 64x64 patch
            sum = psum[t].x; sq = psum[t].y; n = 4096.f;
        } else if (t < 20) {             // p=1: 2x2 group of patches
            const int g = t - 16, gr = g >> 1, gc = g & 1;
            const int b = 8 * gr + 2 * gc;
            sum = psum[b].x + psum[b + 1].x + psum[b + 4].x + psum[b + 5].x;
            sq  = psum[b].y + psum[b + 1].y + psum[b + 4].y + psum[b + 5].y;
            n = 16384.f;
        } else {                         // p=0: full channel
            sum = 0.f; sq = 0.f;
#pragma unroll
            for (int i = 0; i < 16; ++i) { sum += psum[i].x; sq += psum[i].y; }
            n = 65536.f;
        }
        const float mu   = sum / n;
        const float var  = sq / n - mu * mu;
        const float rstd = rsqrtf(var + EPS);
        coef[t] = make_float2(-rstd * LOG2E, mu * rstd * LOG2E);
    }

    // softmax of level weights (wave-uniform, overlaps with barrier)
    const float w0 = lw[0], w1 = lw[1], w2 = lw[2];
    const float mx  = fmaxf(w0, fmaxf(w1, w2));
    const float ex0 = __expf(w0 - mx), ex1 = __expf(w1 - mx), ex2 = __expf(w2 - mx);
    const float inv = __builtin_amdgcn_rcpf(ex0 + ex1 + ex2);
    const float lwA = ex0 * inv;   // p=2 (64x64)
    const float lwB = ex1 * inv;   // p=1 (128x128)
    const float lwC = ex2 * inv;   // p=0 (full)

    __syncthreads();

    // ---- Phase 2: output (re-read hits L2/L3) ----
#pragma unroll
    for (int kb = 0; kb < 4; ++kb) {
        const float2 c2 = coef[kb * 4 + pc];
        const float2 c1 = coef[16 + (kb >> 1) * 2 + (pc >> 1)];
        const float2 c0 = coef[20];
#pragma unroll 4
        for (int kk = 0; kk < 16; ++kk) {
            const long idx = base + (kb * 16 + kk) * 256 + t;
            const float4 v = x4[idx];
            float4 r;
#define ELT(comp)                                                              \
            {                                                                  \
                const float xv = v.comp;                                       \
                const float e2 = __builtin_amdgcn_exp2f(fmaf(xv, c2.x, c2.y)); \
                const float e1 = __builtin_amdgcn_exp2f(fmaf(xv, c1.x, c1.y)); \
                const float e0 = __builtin_amdgcn_exp2f(fmaf(xv, c0.x, c0.y)); \
                const float pA = 1.f + e2, pB = 1.f + e1, pC = 1.f + e0;       \
                const float mBC = pB * pC, mAB = pA * pB;                      \
                const float mAC = pA * pC;                                     \
                const float num = fmaf(lwA, mBC, fmaf(lwB, mAC, lwC * mAB));   \
                const float den = mAB * pC;                                    \
                const float t0  = 0.5f * xv;                                   \
                r.comp = fmaf(t0 * num, __builtin_amdgcn_rcpf(den), t0);       \
            }
            ELT(x) ELT(y) ELT(z) ELT(w)
#undef ELT
            out4[idx] = r;
        }
    }
}

extern "C" void kernel_launch(void* const* d_in, const int* in_sizes, int n_in,
                              void* d_out, int out_size, void* d_ws, size_t ws_size,
                              hipStream_t stream) {
    const float* x  = (const float*)d_in[0];
    const float* lw = (const float*)d_in[1];
    float* out      = (float*)d_out;
    k_fused<<<512, 256, 0, stream>>>((const float4*)x, lw, (float4*)out);
}

// Round 3
// 248.129 us; speedup vs baseline: 1.0068x; 1.0068x over previous
//
#include <hip/hip_runtime.h>

#define EPS 1e-5f
#define LOG2E 1.4426950408889634f

// ---------------------------------------------------------------------------
// Workspace layout (float2-granular):
//   part : 8192 float2   (per-64x64-patch sum/sumsq)
//   S    : 512*21 float2 (exp2-folded coefs: A=-rstd*log2e, B=mu*rstd*log2e)
//   lws  : 4 float       (softmaxed level weights, written by k_agg block 0)
// ---------------------------------------------------------------------------

// K1: per-64x64-patch partial sums. 8192 blocks x 256 threads (32 blocks/CU),
// pure streaming read of x (134 MB) -> read-BW-bound.
__global__ __launch_bounds__(256) void k_stats(const float4* __restrict__ x4,
                                               float2* __restrict__ part) {
    const int P    = blockIdx.x;        // bc*16 + pr*4 + pc
    const int bc   = P >> 4;
    const int pidx = P & 15;
    const int pr   = pidx >> 2, pc = pidx & 3;
    const int t    = threadIdx.x;
    const long chan4 = (long)bc << 14;  // 16384 float4 per channel

    float s = 0.f, ss = 0.f;
#pragma unroll
    for (int k = 0; k < 4; ++k) {
        const int q    = k * 256 + t;   // 0..1023 float4 within patch
        const int row  = q >> 4;        // 0..63
        const int col4 = q & 15;        // 0..15
        const float4 v = x4[chan4 + (long)(pr * 64 + row) * 64 + pc * 16 + col4];
        s  += v.x + v.y + v.z + v.w;
        ss += v.x * v.x + v.y * v.y + v.z * v.z + v.w * v.w;
    }
#pragma unroll
    for (int off = 32; off > 0; off >>= 1) {
        s  += __shfl_down(s, off, 64);
        ss += __shfl_down(ss, off, 64);
    }
    __shared__ float2 red[4];
    const int wave = t >> 6, lane = t & 63;
    if (lane == 0) red[wave] = make_float2(s, ss);
    __syncthreads();
    if (t == 0) {
        float S = 0.f, SS = 0.f;
#pragma unroll
        for (int i = 0; i < 4; ++i) { S += red[i].x; SS += red[i].y; }
        part[P] = make_float2(S, SS);
    }
}

// K2: aggregate patch sums -> 21 coef slots per channel; block 0 also writes
// the softmaxed level weights. 512 blocks x 64 threads, ~3 us.
__global__ __launch_bounds__(64) void k_agg(const float2* __restrict__ part,
                                            const float* __restrict__ lw,
                                            float2* __restrict__ S,
                                            float* __restrict__ lws) {
    const int bc = blockIdx.x;
    const int t  = threadIdx.x;
    __shared__ float2 ps[16];
    if (t < 16) ps[t] = part[bc * 16 + t];
    __syncthreads();

    if (t < 21) {
        float sum = 0.f, sq = 0.f, n;
        if (t < 16) {                    // p=2: one 64x64 patch
            sum = ps[t].x; sq = ps[t].y; n = 4096.f;
        } else if (t < 20) {             // p=1: 2x2 patch group
            const int g = t - 16, gr = g >> 1, gc = g & 1;
            const int b = 8 * gr + 2 * gc;
            sum = ps[b].x + ps[b + 1].x + ps[b + 4].x + ps[b + 5].x;
            sq  = ps[b].y + ps[b + 1].y + ps[b + 4].y + ps[b + 5].y;
            n = 16384.f;
        } else {                         // p=0: full channel
#pragma unroll
            for (int i = 0; i < 16; ++i) { sum += ps[i].x; sq += ps[i].y; }
            n = 65536.f;
        }
        const float mu   = sum / n;
        const float var  = sq / n - mu * mu;
        const float rstd = rsqrtf(var + EPS);
        S[bc * 21 + t] = make_float2(-rstd * LOG2E, mu * rstd * LOG2E);
    }
    if (bc == 0 && t == 21) {
        const float w0 = lw[0], w1 = lw[1], w2 = lw[2];
        const float mx = fmaxf(w0, fmaxf(w1, w2));
        const float e0 = __expf(w0 - mx), e1 = __expf(w1 - mx), e2 = __expf(w2 - mx);
        const float inv = 1.f / (e0 + e1 + e2);
        lws[0] = e0 * inv;   // pairs with p=2 (64x64)
        lws[1] = e1 * inv;   // pairs with p=1 (128x128)
        lws[2] = e2 * inv;   // pairs with p=0 (full)
    }
}

// K3: elementwise apply. 32768 blocks x 256 threads, 1 float4/thread.
// x read is L3-resident after K1; bound by write BW / trans pipe.
__global__ __launch_bounds__(256) void k_apply(const float4* __restrict__ x4,
                                               const float2* __restrict__ S,
                                               const float* __restrict__ lws,
                                               float4* __restrict__ out4) {
    const long i = (long)blockIdx.x * 256 + threadIdx.x;  // float4 index
    const int bc = (int)(i >> 14);
    const int f  = (int)(i & 16383);
    const int h  = f >> 6;        // row 0..255
    const int w4 = f & 63;        // float4 col 0..63

    const float lwA = lws[0], lwB = lws[1], lwC = lws[2];
    const float2* Sc = S + bc * 21;
    const float2 c2 = Sc[(h >> 6) * 4 + (w4 >> 4)];
    const float2 c1 = Sc[16 + (h >> 7) * 2 + (w4 >> 5)];
    const float2 c0 = Sc[20];

    const float4 v = x4[i];
    float4 r;
#define ELT(comp)                                                              \
    {                                                                          \
        const float xv = v.comp;                                               \
        const float e2 = __builtin_amdgcn_exp2f(fmaf(xv, c2.x, c2.y));         \
        const float e1 = __builtin_amdgcn_exp2f(fmaf(xv, c1.x, c1.y));         \
        const float e0 = __builtin_amdgcn_exp2f(fmaf(xv, c0.x, c0.y));         \
        const float pA = 1.f + e2, pB = 1.f + e1, pC = 1.f + e0;               \
        const float mBC = pB * pC, mAB = pA * pB, mAC = pA * pC;               \
        const float num = fmaf(lwA, mBC, fmaf(lwB, mAC, lwC * mAB));           \
        const float den = mAB * pC;                                            \
        const float t0  = 0.5f * xv;                                           \
        r.comp = fmaf(t0 * num, __builtin_amdgcn_rcpf(den), t0);               \
    }
    ELT(x) ELT(y) ELT(z) ELT(w)
#undef ELT
    out4[i] = r;
}

extern "C" void kernel_launch(void* const* d_in, const int* in_sizes, int n_in,
                              void* d_out, int out_size, void* d_ws, size_t ws_size,
                              hipStream_t stream) {
    const float* x  = (const float*)d_in[0];
    const float* lw = (const float*)d_in[1];
    float* out      = (float*)d_out;

    float2* part = (float2*)d_ws;            // 8192 float2
    float2* S    = part + 8192;              // 512*21 float2
    float*  lws  = (float*)(S + 512 * 21);   // 4 floats

    k_stats<<<8192, 256, 0, stream>>>((const float4*)x, part);
    k_agg<<<512, 64, 0, stream>>>(part, lw, S, lws);
    k_apply<<<32768, 256, 0, stream>>>((const float4*)x, S, lws, (float4*)out);
}